// Round 1
// 81.288 us; speedup vs baseline: 1.0111x; 1.0111x over previous
//
#include <hip/hip_runtime.h>
#include <math.h>

#define MLEN 4096
#define RANK 16
#define NROWS 1024
#define LNB 4            // n-rows per mix block (was 8: halved to double wave count)

// Module-static global scratch for the FFT'd H (16 x 4096 complex = 512 KB).
// No hipMalloc, graph-capture safe; fully rewritten every kernel_launch call.
__device__ float2 g_Hft[RANK * MLEN];

// stable softplus: max(x,0) + log1p(exp(-|x|))
__device__ __forceinline__ float softplus_f(float x) {
    return fmaxf(x, 0.0f) + log1pf(__expf(-fabsf(x)));
}

// LDS padding map: +1 float2 every 16 elements. Verified: turns the stride-4
// quad access of every remaining pass (and the final linear read) into <=4-way
// bank-pair conflicts (was 16-way at s=0/2, 32-way on the bit-reversed write).
#define MAP(i) ((i) + ((i) >> 4))

// Radix-2 DIT FFT of softplus(H[row,:]). v2: the first TWO stages (one radix-4
// butterfly, twiddle-free since p=0) are done in REGISTERS on the 4 real
// inputs each thread owns after bit-reversal:
//   buf[4t+q] = x[brev12(4t+q)] = x[rev10(t) + 1024*{0,2,1,3}[q]]
// This removes the bit-reversed LDS write pass and the worst-conflict pass.
// Remaining 5 passes (s=2..10, two stages fused each) identical math to the
// proven v1, with MAP() padding on all LDS accesses.
__global__ __launch_bounds__(1024) void fft_rows_kernel(const float* __restrict__ H) {
    __shared__ float2 buf[MLEN + MLEN / 16];
    const int row = blockIdx.x;
    const int t   = threadIdx.x;
    const float* h = H + row * MLEN;

    // ---- stages 0+1 in registers (real inputs, twiddles are 1 and -i) ----
    const int r10 = (int)(__brev((unsigned)t) >> 22);    // rev10(t)
    const float a0 = softplus_f(h[r10]);                 // pos 4t+0
    const float a1 = softplus_f(h[r10 + 2048]);          // pos 4t+1
    const float a2 = softplus_f(h[r10 + 1024]);          // pos 4t+2
    const float a3 = softplus_f(h[r10 + 3072]);          // pos 4t+3
    const float u0 = a0 + a1, u1 = a0 - a1;
    const float u2 = a2 + a3, u3 = a2 - a3;
    const int k0 = t << 2;
    buf[MAP(k0)]     = make_float2(u0 + u2, 0.0f);       // u0 + 1*u2
    buf[MAP(k0 + 1)] = make_float2(u1, -u3);             // u1 + (-i)*u3 (real u3)
    buf[MAP(k0 + 2)] = make_float2(u0 - u2, 0.0f);
    buf[MAP(k0 + 3)] = make_float2(u1, u3);
    __syncthreads();

    // ---- stages 2..11, two per pass (radix-4 dataflow) ----
    #pragma unroll
    for (int s = 2; s < 12; s += 2) {
        const int h1 = 1 << s;
        const int p  = t & (h1 - 1);
        const int k  = ((t >> s) << (s + 2)) + p;
        const float rA = (float)p * (1.0f / (float)(h1 << 2));  // p/len2, revolutions
        const float ca = __builtin_amdgcn_cosf(rA);             // wA = (ca,-sa)
        const float sa = __builtin_amdgcn_sinf(rA);
        const float c1 = ca * ca - sa * sa;                     // w1 = wA^2
        const float s1 = 2.0f * ca * sa;

        const float2 a0c = buf[MAP(k)];
        const float2 a1c = buf[MAP(k + h1)];
        const float2 a2c = buf[MAP(k + 2 * h1)];
        const float2 a3c = buf[MAP(k + 3 * h1)];

        // stage s: pairs (k,k+h1) and (k+2h1,k+3h1), twiddle w1=(c1,-s1)
        const float2 w1a1 = make_float2(c1 * a1c.x + s1 * a1c.y, c1 * a1c.y - s1 * a1c.x);
        const float2 w1a3 = make_float2(c1 * a3c.x + s1 * a3c.y, c1 * a3c.y - s1 * a3c.x);
        const float2 v0 = make_float2(a0c.x + w1a1.x, a0c.y + w1a1.y);
        const float2 v1 = make_float2(a0c.x - w1a1.x, a0c.y - w1a1.y);
        const float2 v2 = make_float2(a2c.x + w1a3.x, a2c.y + w1a3.y);
        const float2 v3 = make_float2(a2c.x - w1a3.x, a2c.y - w1a3.y);

        // stage s+1: twiddles wA and wB = -i*wA
        const float2 wAv2 = make_float2(ca * v2.x + sa * v2.y, ca * v2.y - sa * v2.x);
        const float2 w    = make_float2(ca * v3.x + sa * v3.y, ca * v3.y - sa * v3.x);
        const float2 wBv3 = make_float2(w.y, -w.x);             // -i * w

        buf[MAP(k)]          = make_float2(v0.x + wAv2.x, v0.y + wAv2.y);
        buf[MAP(k + h1)]     = make_float2(v1.x + wBv3.x, v1.y + wBv3.y);
        buf[MAP(k + 2 * h1)] = make_float2(v0.x - wAv2.x, v0.y - wAv2.y);
        buf[MAP(k + 3 * h1)] = make_float2(v1.x - wBv3.x, v1.y - wBv3.y);
        __syncthreads();
    }

    for (int i = t; i < MLEN; i += 1024) {
        g_Hft[row * MLEN + i] = buf[MAP(i)];
    }
}

// Mirror-pair mix (real-part output): thread owns a in [1,2048]; each (ln,d)
// iteration yields BOTH out[n,a] and out[n,4096-a] via conjugate symmetry.
// v2: params packed (sw,tv,qc,qi) -> ONE uniform ds_read_b128 per inner iter
// (was 4x ds_read_b32); LNB 4 (was 8) doubles resident waves to 8/SIMD.
__global__ __launch_bounds__(256, 6) void mix_mirror_kernel(const float* __restrict__ W,
                                                            const float* __restrict__ tau,
                                                            float* __restrict__ out) {
    __shared__ __align__(16) float4 prm[LNB * RANK];   // (sw, tv, qc, qi)

    const int tid = threadIdx.x;
    const int n0  = blockIdx.y * LNB;

    if (tid < LNB * RANK) {   // 64 threads: one (ln,d) each
        const float sw = softplus_f(W[n0 * RANK + tid]);
        const float tv = tau[n0 * RANK + tid];
        const float c2 = __builtin_amdgcn_cosf(tv);    // cos(2*pi*tau)
        const float s2 = __builtin_amdgcn_sinf(tv);
        prm[tid] = make_float4(sw, tv, sw * c2, -sw * s2);
    }
    __syncthreads();

    const int a  = blockIdx.x * 256 + tid + 1;        // 1..2048
    const int mm = MLEN - a;                          // 2048..4095
    const float fa = (float)a * (1.0f / (float)MLEN);

    float2 h[RANK];
    #pragma unroll
    for (int d = 0; d < RANK; ++d) h[d] = g_Hft[d * MLEN + a];

    #pragma unroll 1
    for (int ln = 0; ln < LNB; ++ln) {
        float ar = 0.0f, aw = 0.0f;
        #pragma unroll
        for (int d = 0; d < RANK; ++d) {
            const float4 P = prm[ln * RANK + d];      // sw, tv, qc, qi
            const float r  = P.y * fa;                // revolutions, [0,1)
            const float c  = __builtin_amdgcn_cosf(r);
            const float s  = __builtin_amdgcn_sinf(r);
            const float tre = fmaf(s, h[d].y, c * h[d].x);
            const float tim = fmaf(c, h[d].y, -s * h[d].x);
            ar = fmaf(P.x, tre, ar);
            aw = fmaf(P.z, tre, fmaf(P.w, tim, aw));
        }
        const int rowbase = (n0 + ln) * MLEN;
        out[rowbase + a]  = ar;
        out[rowbase + mm] = aw;
    }

    // m = 0: V[n,0] = sum_d sw * Hft[d,0].x  (phase = 1, DC bin real)
    if (blockIdx.x == 0 && tid == 0) {
        float h0[RANK];
        #pragma unroll
        for (int d = 0; d < RANK; ++d) h0[d] = g_Hft[d * MLEN].x;
        for (int ln = 0; ln < LNB; ++ln) {
            float v = 0.0f;
            #pragma unroll
            for (int d = 0; d < RANK; ++d) v = fmaf(prm[ln * RANK + d].x, h0[d], v);
            out[(n0 + ln) * MLEN] = v;
        }
    }
}

// Guarded generic fallback (interleaved complex), only used if out_size != N*M.
__global__ __launch_bounds__(256) void mix_generic_kernel(const float* __restrict__ W,
                                                          const float* __restrict__ tau,
                                                          float* __restrict__ out,
                                                          int out_size_floats) {
    __shared__ float sw_s[256];
    __shared__ float tau_s[256];
    const int tid = threadIdx.x;
    const int m   = blockIdx.x * 256 + tid;
    const int n0  = blockIdx.y * 16;
    sw_s[tid]  = softplus_f(W[n0 * RANK + tid]);
    tau_s[tid] = tau[n0 * RANK + tid];
    __syncthreads();
    float2 h[RANK];
    #pragma unroll
    for (int d = 0; d < RANK; ++d) h[d] = g_Hft[d * MLEN + m];
    const float fm = (float)m * (1.0f / (float)MLEN);
    #pragma unroll 1
    for (int ln = 0; ln < 16; ++ln) {
        float ar = 0.0f, ai = 0.0f;
        #pragma unroll
        for (int d = 0; d < RANK; ++d) {
            const float r = tau_s[ln * RANK + d] * fm;
            const float c = __builtin_amdgcn_cosf(r);
            const float s = __builtin_amdgcn_sinf(r);
            const float sw = sw_s[ln * RANK + d];
            ar = fmaf(sw, fmaf(s, h[d].y, c * h[d].x), ar);
            ai = fmaf(sw, fmaf(c, h[d].y, -s * h[d].x), ai);
        }
        const long long fi = 2LL * ((long long)(n0 + ln) * MLEN + m);
        if (fi + 1 < (long long)out_size_floats) {
            out[fi]     = ar;
            out[fi + 1] = ai;
        }
    }
}

extern "C" void kernel_launch(void* const* d_in, const int* in_sizes, int n_in,
                              void* d_out, int out_size, void* d_ws, size_t ws_size,
                              hipStream_t stream) {
    const float* W   = (const float*)d_in[0];   // (1024, 16)
    const float* H   = (const float*)d_in[1];   // (16, 4096)
    const float* tau = (const float*)d_in[2];   // (1024, 16)
    float* out = (float*)d_out;
    (void)d_ws; (void)ws_size; (void)in_sizes; (void)n_in;

    fft_rows_kernel<<<dim3(RANK), dim3(1024), 0, stream>>>(H);

    if (out_size == NROWS * MLEN) {
        // pairs a in [1,2048] -> grid.x = 2048/256 = 8; n-tiles of LNB
        mix_mirror_kernel<<<dim3(8, NROWS / LNB), dim3(256), 0, stream>>>(W, tau, out);
    } else {
        mix_generic_kernel<<<dim3(MLEN / 256, NROWS / 16), dim3(256), 0, stream>>>(
            W, tau, out, out_size);
    }
}

// Round 2
// 81.016 us; speedup vs baseline: 1.0145x; 1.0033x over previous
//
#include <hip/hip_runtime.h>
#include <math.h>

#define MLEN 4096
#define RANK 16
#define NROWS 1024
#define LNB 4            // n-rows per mix block

// Module-static global scratch for the FFT'd H (16 x 4096 complex = 512 KB).
// No hipMalloc, graph-capture safe; fully rewritten every kernel_launch call.
__device__ float2 g_Hft[RANK * MLEN];

// stable softplus: max(x,0) + log1p(exp(-|x|))
__device__ __forceinline__ float softplus_f(float x) {
    return fmaxf(x, 0.0f) + log1pf(__expf(-fabsf(x)));
}

// LDS padding map for float2 indices: +1 float2 every 16. Turns the stride-4
// quad access of every pass into <=4-way conflicts.
#define MAP(i) ((i) + ((i) >> 4))
// LDS padding map for float (staging) indices: wave reads are {16v+c} (v=0..63,
// 32-way on 32 banks); +(i>>4) makes them {17v+c'} -> 2-way (free).
#define SMAP(i) ((i) + ((i) >> 4))

// Radix-2 DIT FFT of softplus(H[row,:]). v3: input row is first staged into
// LDS with ONE coalesced float4 load per thread (was: 4 scattered global
// loads, 64 txns each); the bit-reversed gather then happens in LDS. First
// two stages (twiddle-free radix-4 on real inputs) stay in registers.
__global__ __launch_bounds__(1024) void fft_rows_kernel(const float* __restrict__ H) {
    __shared__ float2 buf[MLEN + MLEN / 16];
    const int row = blockIdx.x;
    const int t   = threadIdx.x;
    const float* h = H + row * MLEN;

    // ---- stage input coalesced into LDS (as floats, padded) ----
    float* sf = (float*)buf;
    const float4 x4 = reinterpret_cast<const float4*>(h)[t];
    const int i0 = t << 2;
    sf[SMAP(i0)]     = x4.x;
    sf[SMAP(i0 + 1)] = x4.y;
    sf[SMAP(i0 + 2)] = x4.z;
    sf[SMAP(i0 + 3)] = x4.w;
    __syncthreads();

    // ---- bit-reversed gather + stages 0+1 in registers ----
    const int r10 = (int)(__brev((unsigned)t) >> 22);    // rev10(t)
    const float a0 = softplus_f(sf[SMAP(r10)]);          // pos 4t+0
    const float a1 = softplus_f(sf[SMAP(r10 + 2048)]);   // pos 4t+1
    const float a2 = softplus_f(sf[SMAP(r10 + 1024)]);   // pos 4t+2
    const float a3 = softplus_f(sf[SMAP(r10 + 3072)]);   // pos 4t+3
    __syncthreads();                                     // staging reads done
    const float u0 = a0 + a1, u1 = a0 - a1;
    const float u2 = a2 + a3, u3 = a2 - a3;
    const int k0 = t << 2;
    buf[MAP(k0)]     = make_float2(u0 + u2, 0.0f);       // u0 + 1*u2
    buf[MAP(k0 + 1)] = make_float2(u1, -u3);             // u1 + (-i)*u3 (real u3)
    buf[MAP(k0 + 2)] = make_float2(u0 - u2, 0.0f);
    buf[MAP(k0 + 3)] = make_float2(u1, u3);
    __syncthreads();

    // ---- stages 2..11, two per pass (radix-4 dataflow) ----
    #pragma unroll
    for (int s = 2; s < 12; s += 2) {
        const int h1 = 1 << s;
        const int p  = t & (h1 - 1);
        const int k  = ((t >> s) << (s + 2)) + p;
        const float rA = (float)p * (1.0f / (float)(h1 << 2));  // p/len2, revolutions
        const float ca = __builtin_amdgcn_cosf(rA);             // wA = (ca,-sa)
        const float sa = __builtin_amdgcn_sinf(rA);
        const float c1 = ca * ca - sa * sa;                     // w1 = wA^2
        const float s1 = 2.0f * ca * sa;

        const float2 a0c = buf[MAP(k)];
        const float2 a1c = buf[MAP(k + h1)];
        const float2 a2c = buf[MAP(k + 2 * h1)];
        const float2 a3c = buf[MAP(k + 3 * h1)];

        // stage s: pairs (k,k+h1) and (k+2h1,k+3h1), twiddle w1=(c1,-s1)
        const float2 w1a1 = make_float2(c1 * a1c.x + s1 * a1c.y, c1 * a1c.y - s1 * a1c.x);
        const float2 w1a3 = make_float2(c1 * a3c.x + s1 * a3c.y, c1 * a3c.y - s1 * a3c.x);
        const float2 v0 = make_float2(a0c.x + w1a1.x, a0c.y + w1a1.y);
        const float2 v1 = make_float2(a0c.x - w1a1.x, a0c.y - w1a1.y);
        const float2 v2 = make_float2(a2c.x + w1a3.x, a2c.y + w1a3.y);
        const float2 v3 = make_float2(a2c.x - w1a3.x, a2c.y - w1a3.y);

        // stage s+1: twiddles wA and wB = -i*wA
        const float2 wAv2 = make_float2(ca * v2.x + sa * v2.y, ca * v2.y - sa * v2.x);
        const float2 w    = make_float2(ca * v3.x + sa * v3.y, ca * v3.y - sa * v3.x);
        const float2 wBv3 = make_float2(w.y, -w.x);             // -i * w

        buf[MAP(k)]          = make_float2(v0.x + wAv2.x, v0.y + wAv2.y);
        buf[MAP(k + h1)]     = make_float2(v1.x + wBv3.x, v1.y + wBv3.y);
        buf[MAP(k + 2 * h1)] = make_float2(v0.x - wAv2.x, v0.y - wAv2.y);
        buf[MAP(k + 3 * h1)] = make_float2(v1.x - wBv3.x, v1.y - wBv3.y);
        __syncthreads();
    }

    for (int i = t; i < MLEN; i += 1024) {
        g_Hft[row * MLEN + i] = buf[MAP(i)];
    }
}

// Mirror-pair mix. v3: each thread owns TWO frequency columns, a in [1,1024]
// and b = a+1024, plus their conjugate mirrors -> 4 outputs per (n) row.
// Phase for b is the a-phase rotated by the per-(n,d) constant
//   e^{-2pi i * tau/4}  (precomputed rc,rs in LDS),
// halving the sin/cos count per output column. Per-(n,d) params:
//   prm4 = (sw, tv, qc, qi), prm2 = (rc, rs)
// with qc = sw*cos(2pi tau), qi = -sw*sin(2pi tau) (mirror-column weights).
__global__ __launch_bounds__(256, 4) void mix_mirror_kernel(const float* __restrict__ W,
                                                            const float* __restrict__ tau,
                                                            float* __restrict__ out) {
    __shared__ __align__(16) float4 prm4[LNB * RANK];
    __shared__ __align__(16) float2 prm2[LNB * RANK];

    const int tid = threadIdx.x;
    const int n0  = blockIdx.y * LNB;

    if (tid < LNB * RANK) {   // 64 threads: one (ln,d) each
        const float sw = softplus_f(W[n0 * RANK + tid]);
        const float tv = tau[n0 * RANK + tid];
        const float c2 = __builtin_amdgcn_cosf(tv);          // cos(2*pi*tau)
        const float s2 = __builtin_amdgcn_sinf(tv);
        const float rc = __builtin_amdgcn_cosf(0.25f * tv);  // cos(2*pi*tau/4)
        const float rs = __builtin_amdgcn_sinf(0.25f * tv);
        prm4[tid] = make_float4(sw, tv, sw * c2, -sw * s2);
        prm2[tid] = make_float2(rc, rs);
    }
    __syncthreads();

    const int a  = blockIdx.x * 256 + tid + 1;        // 1..1024
    const int b  = a + 1024;                          // 1025..2048
    const float fa = (float)a * (1.0f / (float)MLEN);

    float2 h0[RANK], h1[RANK];
    #pragma unroll
    for (int d = 0; d < RANK; ++d) {
        h0[d] = g_Hft[d * MLEN + a];
        h1[d] = g_Hft[d * MLEN + b];
    }

    #pragma unroll 1
    for (int ln = 0; ln < LNB; ++ln) {
        float ar0 = 0.0f, aw0 = 0.0f;   // columns a, MLEN-a
        float ar1 = 0.0f, aw1 = 0.0f;   // columns b, MLEN-b
        #pragma unroll
        for (int d = 0; d < RANK; ++d) {
            const float4 P = prm4[ln * RANK + d];     // sw, tv, qc, qi
            const float2 R = prm2[ln * RANK + d];     // rc, rs
            const float r  = P.y * fa;                // revolutions, [0,1)
            const float c  = __builtin_amdgcn_cosf(r);
            const float s  = __builtin_amdgcn_sinf(r);
            // column a
            const float tre0 = fmaf(s, h0[d].y, c * h0[d].x);
            const float tim0 = fmaf(c, h0[d].y, -s * h0[d].x);
            ar0 = fmaf(P.x, tre0, ar0);
            aw0 = fmaf(P.z, tre0, fmaf(P.w, tim0, aw0));
            // column b = a+1024: rotate phasor by (rc, rs)
            const float cb = fmaf(c, R.x, -s * R.y);
            const float sb = fmaf(s, R.x,  c * R.y);
            const float tre1 = fmaf(sb, h1[d].y, cb * h1[d].x);
            const float tim1 = fmaf(cb, h1[d].y, -sb * h1[d].x);
            ar1 = fmaf(P.x, tre1, ar1);
            aw1 = fmaf(P.z, tre1, fmaf(P.w, tim1, aw1));
        }
        const int rowbase = (n0 + ln) * MLEN;
        out[rowbase + a]          = ar0;
        out[rowbase + MLEN - a]   = aw0;
        out[rowbase + b]          = ar1;
        out[rowbase + MLEN - b]   = aw1;   // b=2048 double-writes col 2048 (consistent)
    }

    // m = 0: V[n,0] = sum_d sw * Hft[d,0].x  (phase = 1, DC bin real)
    if (blockIdx.x == 0 && tid == 0) {
        float hdc[RANK];
        #pragma unroll
        for (int d = 0; d < RANK; ++d) hdc[d] = g_Hft[d * MLEN].x;
        for (int ln = 0; ln < LNB; ++ln) {
            float v = 0.0f;
            #pragma unroll
            for (int d = 0; d < RANK; ++d) v = fmaf(prm4[ln * RANK + d].x, hdc[d], v);
            out[(n0 + ln) * MLEN] = v;
        }
    }
}

// Guarded generic fallback (interleaved complex), only used if out_size != N*M.
__global__ __launch_bounds__(256) void mix_generic_kernel(const float* __restrict__ W,
                                                          const float* __restrict__ tau,
                                                          float* __restrict__ out,
                                                          int out_size_floats) {
    __shared__ float sw_s[256];
    __shared__ float tau_s[256];
    const int tid = threadIdx.x;
    const int m   = blockIdx.x * 256 + tid;
    const int n0  = blockIdx.y * 16;
    sw_s[tid]  = softplus_f(W[n0 * RANK + tid]);
    tau_s[tid] = tau[n0 * RANK + tid];
    __syncthreads();
    float2 h[RANK];
    #pragma unroll
    for (int d = 0; d < RANK; ++d) h[d] = g_Hft[d * MLEN + m];
    const float fm = (float)m * (1.0f / (float)MLEN);
    #pragma unroll 1
    for (int ln = 0; ln < 16; ++ln) {
        float ar = 0.0f, ai = 0.0f;
        #pragma unroll
        for (int d = 0; d < RANK; ++d) {
            const float r = tau_s[ln * RANK + d] * fm;
            const float c = __builtin_amdgcn_cosf(r);
            const float s = __builtin_amdgcn_sinf(r);
            const float sw = sw_s[ln * RANK + d];
            ar = fmaf(sw, fmaf(s, h[d].y, c * h[d].x), ar);
            ai = fmaf(sw, fmaf(c, h[d].y, -s * h[d].x), ai);
        }
        const long long fi = 2LL * ((long long)(n0 + ln) * MLEN + m);
        if (fi + 1 < (long long)out_size_floats) {
            out[fi]     = ar;
            out[fi + 1] = ai;
        }
    }
}

extern "C" void kernel_launch(void* const* d_in, const int* in_sizes, int n_in,
                              void* d_out, int out_size, void* d_ws, size_t ws_size,
                              hipStream_t stream) {
    const float* W   = (const float*)d_in[0];   // (1024, 16)
    const float* H   = (const float*)d_in[1];   // (16, 4096)
    const float* tau = (const float*)d_in[2];   // (1024, 16)
    float* out = (float*)d_out;
    (void)d_ws; (void)ws_size; (void)in_sizes; (void)n_in;

    fft_rows_kernel<<<dim3(RANK), dim3(1024), 0, stream>>>(H);

    if (out_size == NROWS * MLEN) {
        // column pairs (a, a+1024), a in [1,1024] -> grid.x = 1024/256 = 4
        mix_mirror_kernel<<<dim3(4, NROWS / LNB), dim3(256), 0, stream>>>(W, tau, out);
    } else {
        mix_generic_kernel<<<dim3(MLEN / 256, NROWS / 16), dim3(256), 0, stream>>>(
            W, tau, out, out_size);
    }
}